// Round 7
// baseline (890.773 us; speedup 1.0000x reference)
//
#include <hip/hip_runtime.h>
#include <hip/hip_bf16.h>
#include <math.h>

constexpr int NN  = 51200;   // total nodes
constexpr int EE  = 409600;  // edges (without self loops)
constexpr int BB  = 64;      // graphs
constexpr int APG = 64;      // actions per graph
constexpr int NPG = 800;     // nodes per graph
constexpr int SCAN_N = 2 * NN;
constexpr int NA = BB * APG; // 4096 actions
constexpr int KF = 1056;     // padded MLP input dim (1025 -> 33*32)

typedef __bf16 bf16x8 __attribute__((ext_vector_type(8)));
typedef float f32x4 __attribute__((ext_vector_type(4)));

__device__ __forceinline__ float leaky(float x) { return x > 0.f ? x : 0.2f * x; }
__device__ __forceinline__ unsigned short f2b(float x) {
  __hip_bfloat16 h = __float2bfloat16(x);
  unsigned short u;
  __builtin_memcpy(&u, &h, 2);
  return u;
}

// ---------------- CSR build ----------------
__global__ void count_kernel(const int* __restrict__ ei, int* cnt) {
  int e = blockIdx.x * blockDim.x + threadIdx.x;
  if (e >= EE) return;
  int s = ei[e], d = ei[EE + e];
  atomicAdd(&cnt[d], 1);
  atomicAdd(&cnt[NN + s], 1);
}

__global__ __launch_bounds__(256) void scan1_kernel(const int* __restrict__ cnt,
                                                    int* __restrict__ rp,
                                                    int* __restrict__ bsum) {
  __shared__ int wsum[4];
  int b = blockIdx.x, t = threadIdx.x;
  int base = b * 1024 + t * 4;
  int4 v = *(const int4*)(cnt + base);
  int s = v.x + v.y + v.z + v.w;
  int lane = t & 63, wv = t >> 6;
  int incl = s;
  for (int off = 1; off < 64; off <<= 1) {
    int u = __shfl_up(incl, off);
    if (lane >= off) incl += u;
  }
  if (lane == 63) wsum[wv] = incl;
  __syncthreads();
  int woff = 0;
  for (int i = 0; i < wv; i++) woff += wsum[i];
  int excl = woff + incl - s;
  rp[base] = excl;
  rp[base + 1] = excl + v.x;
  rp[base + 2] = excl + v.x + v.y;
  rp[base + 3] = excl + v.x + v.y + v.z;
  if (t == 255) bsum[b] = woff + incl;
}

__global__ void scan2_kernel(const int* __restrict__ bsum, int* __restrict__ boff,
                             int* __restrict__ rp) {
  __shared__ int w0;
  int t = threadIdx.x;  // 128 threads
  int v = (t < 100) ? bsum[t] : 0;
  int lane = t & 63;
  int incl = v;
  for (int off = 1; off < 64; off <<= 1) {
    int u = __shfl_up(incl, off);
    if (lane >= off) incl += u;
  }
  if (t == 63) w0 = incl;
  __syncthreads();
  int excl = incl - v + ((t >= 64) ? w0 : 0);
  if (t < 100) boff[t] = excl;
  if (t == 99) rp[SCAN_N] = excl + v;
}

__global__ __launch_bounds__(256) void scan3_kernel(int* __restrict__ rp,
                                                    const int* __restrict__ boff) {
  int b = blockIdx.x;
  int off = boff[b];
  int i = b * 1024 + threadIdx.x * 4;
  int4 v = *(int4*)(rp + i);
  v.x += off; v.y += off; v.z += off; v.w += off;
  *(int4*)(rp + i) = v;
}

__global__ void fill_kernel(const int* __restrict__ ei, const int* __restrict__ rp,
                            int* pos, int* __restrict__ col) {
  int e = blockIdx.x * blockDim.x + threadIdx.x;
  if (e >= EE) return;
  int s = ei[e], d = ei[EE + e];
  int p = atomicAdd(&pos[d], 1);
  col[rp[d] + p] = s;
  int q = atomicAdd(&pos[NN + s], 1);
  col[rp[NN + s] + q] = d;
}

// ---------------- layer-1: fin=3 linear + al_s/al_d fused (H=4,C=64) ----------------
__global__ __launch_bounds__(256) void lin1_al_kernel(const float* __restrict__ x,
                                                      const float* __restrict__ W,
                                                      const float* __restrict__ a_src,
                                                      const float* __restrict__ a_dst,
                                                      float* __restrict__ out,
                                                      float* __restrict__ al_s,
                                                      float* __restrict__ al_d,
                                                      int c1, int c2) {
  int n = blockIdx.x;
  int j = threadIdx.x;
  int wv = j >> 6, lane = j & 63;
  float f0 = x[n * 5], f1 = x[n * 5 + c1], f2 = x[n * 5 + c2];
  float v = f0 * W[j] + f1 * W[256 + j] + f2 * W[512 + j];
  out[(size_t)n * 256 + j] = v;
  float ps = v * a_src[j], pd = v * a_dst[j];  // head == wave (C=64)
  for (int off = 1; off < 64; off <<= 1) {
    ps += __shfl_xor(ps, off);
    pd += __shfl_xor(pd, off);
  }
  if (lane == 0) {
    al_s[n * 4 + wv] = ps;
    al_d[n * 4 + wv] = pd;
  }
}

// -------- helper: load per-node attention row als[n*HH .. +HH) --------
template <int HH>
__device__ __forceinline__ void load_al(const float* __restrict__ p, int n, float* v) {
  if constexpr (HH == 4) {
    float4 w = *(const float4*)(p + n * 4);
    v[0] = w.x; v[1] = w.y; v[2] = w.z; v[3] = w.w;
  } else {
    v[0] = p[n];
  }
}

// ---------------- fused softmax + SpMM (4 edges x 16 lanes, XCD-swizzled) ----------
// out[d] = sum_{e in N(d) + self} softmax(leaky(als[src]+ald[d])) * xp[src]
template <int HH, int CC>
__global__ __launch_bounds__(256) void spmm_fused_kernel(const float* __restrict__ xp,
                                                         const float* __restrict__ als,
                                                         const float* __restrict__ ald,
                                                         const int* __restrict__ rp,
                                                         const int* __restrict__ col,
                                                         const float* __restrict__ bias,
                                                         float* __restrict__ out,
                                                         __hip_bfloat16* __restrict__ out_bf,
                                                         int out_off, int do_elu) {
  constexpr int HC = HH * CC;
  constexpr int CPL = HC / 16;   // channels per lane (16 lanes per edge)
  constexpr int NV = CPL / 4;    // float4 loads per row chunk
  int b = blockIdx.x;
  int xcd = b & 7, q = b >> 3;
  int g_id = (q / 200) * 8 + xcd;
  int d = g_id * 800 + (q % 200) * 4 + (threadIdx.x >> 6);
  int lane = threadIdx.x & 63;
  int sub = lane & 15, g = lane >> 4;  // 4 edge groups x 16 lanes
  int h_l = (sub * CPL) / CC;
  int beg = rp[d], end = rp[d + 1];

  float ald_loc[HH], self_lg[HH], tmp[HH];
  load_al<HH>(ald, d, ald_loc);
  load_al<HH>(als, d, tmp);
#pragma unroll
  for (int h = 0; h < HH; h++) self_lg[h] = leaky(tmp[h] + ald_loc[h]);

  // pass A: max over edge logits (all 16 lanes of a group redundantly compute)
  float mx[HH];
#pragma unroll
  for (int h = 0; h < HH; h++) mx[h] = self_lg[h];
  for (int i = beg + g; i < end; i += 4) {
    int s = col[i];
    load_al<HH>(als, s, tmp);
#pragma unroll
    for (int h = 0; h < HH; h++) mx[h] = fmaxf(mx[h], leaky(tmp[h] + ald_loc[h]));
  }
#pragma unroll
  for (int h = 0; h < HH; h++) {
    mx[h] = fmaxf(mx[h], __shfl_xor(mx[h], 16));
    mx[h] = fmaxf(mx[h], __shfl_xor(mx[h], 32));
  }

  // pass B: sum of exp
  float sm[HH];
#pragma unroll
  for (int h = 0; h < HH; h++) sm[h] = 0.f;
  for (int i = beg + g; i < end; i += 4) {
    int s = col[i];
    load_al<HH>(als, s, tmp);
#pragma unroll
    for (int h = 0; h < HH; h++) sm[h] += expf(leaky(tmp[h] + ald_loc[h]) - mx[h]);
  }
#pragma unroll
  for (int h = 0; h < HH; h++) {
    sm[h] += __shfl_xor(sm[h], 16);
    sm[h] += __shfl_xor(sm[h], 32);
  }
  float inv[HH];
#pragma unroll
  for (int h = 0; h < HH; h++)
    inv[h] = 1.f / (sm[h] + expf(self_lg[h] - mx[h]) + 1e-16f);

  // pass C: weighted aggregation (lane handles CPL channels of its group's edges)
  float acc[CPL];
#pragma unroll
  for (int j = 0; j < CPL; j++) acc[j] = 0.f;
  size_t rowoff = (size_t)sub * CPL;
  if (g == 0) {  // self loop
    float a = expf(self_lg[h_l] - mx[h_l]) * inv[h_l];
    const float4* rb = (const float4*)(xp + (size_t)d * HC + rowoff);
#pragma unroll
    for (int q2 = 0; q2 < NV; q2++) {
      float4 w = rb[q2];
      acc[4 * q2 + 0] += a * w.x;
      acc[4 * q2 + 1] += a * w.y;
      acc[4 * q2 + 2] += a * w.z;
      acc[4 * q2 + 3] += a * w.w;
    }
  }
  for (int i = beg + g; i < end; i += 4) {
    int s = col[i];
    float lg = (HH == 1) ? leaky(als[s] + ald_loc[0])
                         : leaky(als[s * HH + h_l] + ald_loc[h_l]);
    float a = expf(lg - mx[h_l]) * inv[h_l];
    const float4* rb = (const float4*)(xp + (size_t)s * HC + rowoff);
#pragma unroll
    for (int q2 = 0; q2 < NV; q2++) {
      float4 w = rb[q2];
      acc[4 * q2 + 0] += a * w.x;
      acc[4 * q2 + 1] += a * w.y;
      acc[4 * q2 + 2] += a * w.z;
      acc[4 * q2 + 3] += a * w.w;
    }
  }
#pragma unroll
  for (int j = 0; j < CPL; j++) {
    acc[j] += __shfl_xor(acc[j], 16);
    acc[j] += __shfl_xor(acc[j], 32);
  }
  if (g == 0) {
    float v[CPL];
#pragma unroll
    for (int j = 0; j < CPL; j++) {
      v[j] = acc[j] + bias[sub * CPL + j];
      if (do_elu) v[j] = v[j] > 0.f ? v[j] : expm1f(v[j]);
    }
    if (out) {
#pragma unroll
      for (int j = 0; j < CPL; j += 4)
        *(float4*)(out + (size_t)d * 256 + out_off + sub * CPL + j) =
            make_float4(v[j], v[j + 1], v[j + 2], v[j + 3]);
    }
    if (out_bf) {
      unsigned* ob = (unsigned*)out_bf + (size_t)d * (HC / 2) + sub * (CPL / 2);
#pragma unroll
      for (int q2 = 0; q2 < CPL / 2; q2++)
        ob[q2] = (unsigned)f2b(v[2 * q2]) | ((unsigned)f2b(v[2 * q2 + 1]) << 16);
    }
  }
}

// ---------------- weight cast + transpose + K-pad: Wt[n][k] ----------------
__global__ void castW_kernel(const float* __restrict__ W, __hip_bfloat16* __restrict__ Wt,
                             int K, int N, int Kp) {
  int idx = blockIdx.x * 256 + threadIdx.x;
  if (idx >= N * Kp) return;
  int n = idx / Kp, k = idx % Kp;
  Wt[idx] = (k < K) ? __float2bfloat16(W[(size_t)k * N + n]) : __float2bfloat16(0.f);
}

// ---------------- bf16 MFMA GEMM: C[M,N] = A[M,K] @ Bt[N,K]^T ----------------
// EPI: 1 = fp32 out, 2 = bf16 tanh(x+bias) out.
// ALH > 0: also emit al_s/al_d = rowwise dot with a_src/a_dst (per-head, ALCC ch/head).
template <int EPI, int ALH, int ALCC>
__global__ __launch_bounds__(256) void gemm_mfma(const __hip_bfloat16* __restrict__ A,
                                                 const __hip_bfloat16* __restrict__ Bt,
                                                 float* __restrict__ Cf,
                                                 __hip_bfloat16* __restrict__ Cb,
                                                 const float* __restrict__ bias,
                                                 const float* __restrict__ asv,
                                                 const float* __restrict__ adv,
                                                 float* __restrict__ al_s,
                                                 float* __restrict__ al_d,
                                                 int M, int N, int K) {
  __shared__ __align__(16) __hip_bfloat16 As[128 * 32];
  __shared__ __align__(16) __hip_bfloat16 Bs[128 * 32];
  int t = threadIdx.x;
  int wave = t >> 6, lane = t & 63;
  int wm = (wave >> 1) * 64, wn = (wave & 1) * 64;
  int bm = blockIdx.y * 128, bn = blockIdx.x * 128;

  int r0 = t >> 2, c0 = (t & 3) * 8;
  const __hip_bfloat16* Ag0 = A + (size_t)(bm + r0) * K + c0;
  const __hip_bfloat16* Ag1 = A + (size_t)(bm + r0 + 64) * K + c0;
  const __hip_bfloat16* Bg0 = Bt + (size_t)(bn + r0) * K + c0;
  const __hip_bfloat16* Bg1 = Bt + (size_t)(bn + r0 + 64) * K + c0;
  __hip_bfloat16* Asp0 = As + r0 * 32 + c0;
  __hip_bfloat16* Asp1 = As + (r0 + 64) * 32 + c0;
  __hip_bfloat16* Bsp0 = Bs + r0 * 32 + c0;
  __hip_bfloat16* Bsp1 = Bs + (r0 + 64) * 32 + c0;

  f32x4 acc[4][4];
#pragma unroll
  for (int i = 0; i < 4; i++)
#pragma unroll
    for (int j = 0; j < 4; j++) acc[i][j] = (f32x4)(0.f);

  int frag_off = (lane & 15) * 32 + (lane >> 4) * 8;
  const __hip_bfloat16* Ab = As + wm * 32 + frag_off;
  const __hip_bfloat16* Bb = Bs + wn * 32 + frag_off;

  for (int k0 = 0; k0 < K; k0 += 32) {
    int4 a0 = *(const int4*)(Ag0 + k0);
    int4 a1 = *(const int4*)(Ag1 + k0);
    int4 b0 = *(const int4*)(Bg0 + k0);
    int4 b1 = *(const int4*)(Bg1 + k0);
    __syncthreads();
    *(int4*)Asp0 = a0;
    *(int4*)Asp1 = a1;
    *(int4*)Bsp0 = b0;
    *(int4*)Bsp1 = b1;
    __syncthreads();
    bf16x8 af[4], bfr[4];
#pragma unroll
    for (int i = 0; i < 4; i++) af[i] = *(const bf16x8*)(Ab + i * 16 * 32);
#pragma unroll
    for (int j = 0; j < 4; j++) bfr[j] = *(const bf16x8*)(Bb + j * 16 * 32);
#pragma unroll
    for (int i = 0; i < 4; i++)
#pragma unroll
      for (int j = 0; j < 4; j++)
        acc[i][j] = __builtin_amdgcn_mfma_f32_16x16x32_bf16(af[i], bfr[j], acc[i][j], 0, 0, 0);
  }

  int cr = (lane >> 4) * 4, cc = lane & 15;

  if constexpr (ALH > 0) {
    int head = (bn + wn) / ALCC;
    float as_c[4], ad_c[4];
#pragma unroll
    for (int j = 0; j < 4; j++) {
      int colx = bn + wn + j * 16 + cc;
      as_c[j] = asv[colx];
      ad_c[j] = adv[colx];
    }
#pragma unroll
    for (int i = 0; i < 4; i++)
#pragma unroll
      for (int r = 0; r < 4; r++) {
        float ps = 0.f, pd = 0.f;
#pragma unroll
        for (int j = 0; j < 4; j++) {
          ps += acc[i][j][r] * as_c[j];
          pd += acc[i][j][r] * ad_c[j];
        }
        ps += __shfl_xor(ps, 1); pd += __shfl_xor(pd, 1);
        ps += __shfl_xor(ps, 2); pd += __shfl_xor(pd, 2);
        ps += __shfl_xor(ps, 4); pd += __shfl_xor(pd, 4);
        ps += __shfl_xor(ps, 8); pd += __shfl_xor(pd, 8);
        if ((lane & 15) == 0) {
          int row = bm + wm + i * 16 + cr + r;
          if (ALCC > 64) {
            atomicAdd(&al_s[row * ALH + head], ps);
            atomicAdd(&al_d[row * ALH + head], pd);
          } else {
            al_s[row * ALH + head] = ps;
            al_d[row * ALH + head] = pd;
          }
        }
      }
  }

#pragma unroll
  for (int i = 0; i < 4; i++)
#pragma unroll
    for (int j = 0; j < 4; j++) {
      int colx = bn + wn + j * 16 + cc;
      float bs = (EPI == 2) ? bias[colx] : 0.f;
#pragma unroll
      for (int r = 0; r < 4; r++) {
        float v = acc[i][j][r];
        size_t off = (size_t)(bm + wm + i * 16 + cr + r) * N + colx;
        if (EPI == 2) {
          Cb[off] = __float2bfloat16(tanhf(v + bs));
        } else {
          Cf[off] = v;
        }
      }
    }
}

// ---------------- graph mean pooling (two stage) ----------------
__global__ void pool1_kernel(const float* __restrict__ h_node, float* __restrict__ part) {
  int g = blockIdx.y, c = blockIdx.x, t = threadIdx.x;
  const float* base = h_node + ((size_t)g * NPG + c * 100) * 256 + t;
  float s = 0.f;
  for (int i = 0; i < 100; i++) s += base[(size_t)i * 256];
  part[(size_t)(g * 8 + c) * 256 + t] = s;
}

__global__ void pool2_kernel(const float* __restrict__ part, float* __restrict__ g_pool) {
  int g = blockIdx.x, t = threadIdx.x;
  float s = 0.f;
  for (int c = 0; c < 8; c++) s += part[(size_t)(g * 8 + c) * 256 + t];
  g_pool[g * 256 + t] = s * (1.f / NPG);
}

// ---------------- build MLP input features (bf16, padded to KF) ----------------
__global__ __launch_bounds__(256) void buildfeat_kernel(const float* __restrict__ h_node,
                                                        const float* __restrict__ g_pool,
                                                        const int* __restrict__ actions,
                                                        const float* __restrict__ tabu,
                                                        const int* __restrict__ batch,
                                                        __hip_bfloat16* __restrict__ feat) {
  int a = (blockIdx.x * blockDim.x + threadIdx.x) >> 6;
  int lane = threadIdx.x & 63;
  if (a >= NA) return;
  int n0 = actions[a * 2], n1 = actions[a * 2 + 1];
  int g = batch[n0];
  float4 v0 = *(const float4*)(h_node + (size_t)n0 * 256 + lane * 4);
  float4 vg = *(const float4*)(g_pool + (size_t)g * 256 + lane * 4);
  float4 v1 = *(const float4*)(h_node + (size_t)n1 * 256 + lane * 4);
  __hip_bfloat16* fr = feat + (size_t)a * KF;
  ushort4 u;
  u = make_ushort4(f2b(v0.x), f2b(v0.y), f2b(v0.z), f2b(v0.w));
  *(ushort4*)(fr + lane * 4) = u;
  u = make_ushort4(f2b(vg.x), f2b(vg.y), f2b(vg.z), f2b(vg.w));
  *(ushort4*)(fr + 256 + lane * 4) = u;
  u = make_ushort4(f2b(v1.x), f2b(v1.y), f2b(v1.z), f2b(v1.w));
  *(ushort4*)(fr + 512 + lane * 4) = u;
  u = make_ushort4(f2b(vg.x), f2b(vg.y), f2b(vg.z), f2b(vg.w));
  *(ushort4*)(fr + 768 + lane * 4) = u;
  if (lane < 8) {
    float t0 = (lane == 0) ? tabu[a] : 0.f;
    u = make_ushort4(f2b(t0), 0, 0, 0);
    *(ushort4*)(fr + 1024 + lane * 4) = u;
  }
}

// ---------------- final layer GEMV: scores = y @ W4 + b4 ----------------
__global__ __launch_bounds__(256) void gemv_kernel(const __hip_bfloat16* __restrict__ y,
                                                   const float* __restrict__ W4,
                                                   const float* __restrict__ b4,
                                                   float* __restrict__ scores) {
  int a = (blockIdx.x * blockDim.x + threadIdx.x) >> 6;
  int lane = threadIdx.x & 63;
  if (a >= NA) return;
  const unsigned* row = (const unsigned*)(y + (size_t)a * 256);
  float s = 0.f;
#pragma unroll
  for (int q = 0; q < 2; q++) {
    unsigned w = row[lane * 2 + q];
    float lo = __uint_as_float(w << 16), hi = __uint_as_float(w & 0xffff0000u);
    s += lo * W4[lane * 4 + 2 * q] + hi * W4[lane * 4 + 2 * q + 1];
  }
  for (int off = 1; off < 64; off <<= 1) s += __shfl_xor(s, off);
  if (lane == 0) scores[a] = s + b4[0];
}

// ---------------- log-softmax + entropy per graph ----------------
__global__ void softmax_kernel(const float* __restrict__ scores, float* __restrict__ out) {
  int g = (blockIdx.x * blockDim.x + threadIdx.x) >> 6;
  int lane = threadIdx.x & 63;
  if (g >= BB) return;
  float s = scores[g * 64 + lane];
  float m = s;
  for (int off = 1; off < 64; off <<= 1) m = fmaxf(m, __shfl_xor(m, off));
  float ex = expf(s - m);
  float sum = ex;
  for (int off = 1; off < 64; off <<= 1) sum += __shfl_xor(sum, off);
  float lp = s - m - logf(sum);
  out[g * 64 + lane] = lp;
  float pe = (ex / sum) * lp;
  for (int off = 1; off < 64; off <<= 1) pe += __shfl_xor(pe, off);
  if (lane == 0) out[BB * APG + g] = -pe;
}

extern "C" void kernel_launch(void* const* d_in, const int* in_sizes, int n_in,
                              void* d_out, int out_size, void* d_ws, size_t ws_size,
                              hipStream_t stream) {
  const float* x = (const float*)d_in[0];
  const int* ei = (const int*)d_in[1];
  const int* batch = (const int*)d_in[2];
  const int* actions = (const int*)d_in[3];
  const float* tabu = (const float*)d_in[4];
  const float* pW1 = (const float*)d_in[29];
  const float* pb1 = (const float*)d_in[30];
  const float* pW2 = (const float*)d_in[31];
  const float* pb2 = (const float*)d_in[32];
  const float* pW3 = (const float*)d_in[33];
  const float* pb3 = (const float*)d_in[34];
  const float* pW4 = (const float*)d_in[35];
  const float* pb4 = (const float*)d_in[36];
  float* out = (float*)d_out;

  char* ws = (char*)d_ws;
  size_t o = 0;
  auto alloc = [&](size_t bytes) -> void* {
    o = (o + 255) & ~(size_t)255;
    void* p = ws + o;
    o += bytes;
    return p;
  };
  int* cnt = (int*)alloc((size_t)4 * NN * 4);  // cnt[2NN] + pos[2NN]
  int* rp = (int*)alloc((size_t)(SCAN_N + 1) * 4);
  int* col = (int*)alloc(((size_t)2 * EE + 64) * 4);
  int* bsum = (int*)alloc(128 * 4);
  int* boff = (int*)alloc(128 * 4);
  float* al_s = (float*)alloc((size_t)NN * 4 * 4);
  float* al_d = (float*)alloc((size_t)NN * 4 * 4);
  float* bufXf = (float*)alloc((size_t)NN * 256 * 4);                   // xp fp32
  __hip_bfloat16* bufA = (__hip_bfloat16*)alloc((size_t)NN * 256 * 2);  // agg out -> GEMM A
  float* h_node = (float*)alloc((size_t)NN * 256 * 4);
  __hip_bfloat16* wt = (__hip_bfloat16*)alloc((size_t)256 * KF * 2);
  float* part = (float*)alloc((size_t)BB * 8 * 256 * 4);
  float* g_pool = (float*)alloc((size_t)BB * 256 * 4);
  float* scores = (float*)alloc((size_t)NA * 4);
  // MLP scratch aliased onto bufXf (dead after last spmm)
  __hip_bfloat16* feat = (__hip_bfloat16*)bufXf;
  __hip_bfloat16* y1 = feat + (size_t)NA * KF;
  __hip_bfloat16* y2 = y1 + (size_t)NA * 256;

  // --- CSR build ---
  hipMemsetAsync(cnt, 0, (size_t)4 * NN * 4, stream);
  count_kernel<<<(EE + 255) / 256, 256, 0, stream>>>(ei, cnt);
  scan1_kernel<<<SCAN_N / 1024, 256, 0, stream>>>(cnt, rp, bsum);
  scan2_kernel<<<1, 128, 0, stream>>>(bsum, boff, rp);
  scan3_kernel<<<SCAN_N / 1024, 256, 0, stream>>>(rp, boff);
  fill_kernel<<<(EE + 255) / 256, 256, 0, stream>>>(ei, rp, cnt + 2 * NN, col);

  const int nwb = NN / 4;  // spmm: wave per node (XCD-swizzled)
  for (int dir = 0; dir < 2; dir++) {
    const int* rpd = dir ? (rp + NN) : rp;
    int base = 5 + dir * 12;
    const float* W0 = (const float*)d_in[base + 0];
    const float* as0 = (const float*)d_in[base + 1];
    const float* ad0 = (const float*)d_in[base + 2];
    const float* b0 = (const float*)d_in[base + 3];
    const float* W1 = (const float*)d_in[base + 4];
    const float* as1 = (const float*)d_in[base + 5];
    const float* ad1 = (const float*)d_in[base + 6];
    const float* b1 = (const float*)d_in[base + 7];
    const float* W2 = (const float*)d_in[base + 8];
    const float* as2 = (const float*)d_in[base + 9];
    const float* ad2 = (const float*)d_in[base + 10];
    const float* b2 = (const float*)d_in[base + 11];
    int c1 = dir ? 2 : 1, c2 = dir ? 4 : 3;

    // layer 1 (fin=3, H=4, C=64)
    lin1_al_kernel<<<NN, 256, 0, stream>>>(x, W0, as0, ad0, bufXf, al_s, al_d, c1, c2);
    spmm_fused_kernel<4, 64><<<nwb, 256, 0, stream>>>(bufXf, al_s, al_d, rpd, col, b0,
                                                      nullptr, bufA, 0, 1);
    // layer 2 (256 -> H4C64), al fused into GEMM epilogue
    castW_kernel<<<(256 * 256 + 255) / 256, 256, 0, stream>>>(W1, wt, 256, 256, 256);
    gemm_mfma<1, 4, 64><<<dim3(2, NN / 128), 256, 0, stream>>>(
        bufA, wt, bufXf, nullptr, nullptr, as1, ad1, al_s, al_d, NN, 256, 256);
    spmm_fused_kernel<4, 64><<<nwb, 256, 0, stream>>>(bufXf, al_s, al_d, rpd, col, b1,
                                                      nullptr, bufA, 0, 1);
    // layer 3 (256 -> H1C128, no elu) -> h_node half (fp32); al fused (atomic halves)
    castW_kernel<<<(128 * 256 + 255) / 256, 256, 0, stream>>>(W2, wt, 256, 128, 256);
    hipMemsetAsync(al_s, 0, (size_t)NN * 4, stream);
    hipMemsetAsync(al_d, 0, (size_t)NN * 4, stream);
    gemm_mfma<1, 1, 128><<<dim3(1, NN / 128), 256, 0, stream>>>(
        bufA, wt, bufXf, nullptr, nullptr, as2, ad2, al_s, al_d, NN, 128, 256);
    spmm_fused_kernel<1, 128><<<nwb, 256, 0, stream>>>(bufXf, al_s, al_d, rpd, col, b2,
                                                       h_node, nullptr, dir * 128, 0);
  }

  pool1_kernel<<<dim3(8, BB), 256, 0, stream>>>(h_node, part);
  pool2_kernel<<<BB, 256, 0, stream>>>(part, g_pool);

  // --- MLP head via MFMA ---
  buildfeat_kernel<<<NA / 4, 256, 0, stream>>>(h_node, g_pool, actions, tabu, batch, feat);
  castW_kernel<<<(256 * KF + 255) / 256, 256, 0, stream>>>(pW1, wt, 1025, 256, KF);
  gemm_mfma<2, 0, 64><<<dim3(2, NA / 128), 256, 0, stream>>>(
      feat, wt, nullptr, y1, pb1, nullptr, nullptr, nullptr, nullptr, NA, 256, KF);
  castW_kernel<<<(256 * 256 + 255) / 256, 256, 0, stream>>>(pW2, wt, 256, 256, 256);
  gemm_mfma<2, 0, 64><<<dim3(2, NA / 128), 256, 0, stream>>>(
      y1, wt, nullptr, y2, pb2, nullptr, nullptr, nullptr, nullptr, NA, 256, 256);
  castW_kernel<<<(256 * 256 + 255) / 256, 256, 0, stream>>>(pW3, wt, 256, 256, 256);
  gemm_mfma<2, 0, 64><<<dim3(2, NA / 128), 256, 0, stream>>>(
      y2, wt, nullptr, y1, pb3, nullptr, nullptr, nullptr, nullptr, NA, 256, 256);
  gemv_kernel<<<NA / 4, 256, 0, stream>>>(y1, pW4, pb4, scores);
  softmax_kernel<<<(BB * 64) / 256, 256, 0, stream>>>(scores, out);
}

// Round 8
// 727.268 us; speedup vs baseline: 1.2248x; 1.2248x over previous
//
#include <hip/hip_runtime.h>
#include <hip/hip_bf16.h>
#include <math.h>

constexpr int NN  = 51200;   // total nodes
constexpr int EE  = 409600;  // edges (without self loops)
constexpr int BB  = 64;      // graphs
constexpr int APG = 64;      // actions per graph
constexpr int NPG = 800;     // nodes per graph
constexpr int SCAN_N = 2 * NN;
constexpr int NA = BB * APG; // 4096 actions
constexpr int KF = 1056;     // padded MLP input dim (1025 -> 33*32)

typedef __bf16 bf16x8 __attribute__((ext_vector_type(8)));
typedef float f32x4 __attribute__((ext_vector_type(4)));

__device__ __forceinline__ float leaky(float x) { return x > 0.f ? x : 0.2f * x; }
__device__ __forceinline__ unsigned short f2b(float x) {
  __hip_bfloat16 h = __float2bfloat16(x);
  unsigned short u;
  __builtin_memcpy(&u, &h, 2);
  return u;
}

// ---------------- CSR build ----------------
__global__ void count_kernel(const int* __restrict__ ei, int* cnt) {
  int e = blockIdx.x * blockDim.x + threadIdx.x;
  if (e >= EE) return;
  int s = ei[e], d = ei[EE + e];
  atomicAdd(&cnt[d], 1);
  atomicAdd(&cnt[NN + s], 1);
}

__global__ __launch_bounds__(256) void scan1_kernel(const int* __restrict__ cnt,
                                                    int* __restrict__ rp,
                                                    int* __restrict__ bsum) {
  __shared__ int wsum[4];
  int b = blockIdx.x, t = threadIdx.x;
  int base = b * 1024 + t * 4;
  int4 v = *(const int4*)(cnt + base);
  int s = v.x + v.y + v.z + v.w;
  int lane = t & 63, wv = t >> 6;
  int incl = s;
  for (int off = 1; off < 64; off <<= 1) {
    int u = __shfl_up(incl, off);
    if (lane >= off) incl += u;
  }
  if (lane == 63) wsum[wv] = incl;
  __syncthreads();
  int woff = 0;
  for (int i = 0; i < wv; i++) woff += wsum[i];
  int excl = woff + incl - s;
  rp[base] = excl;
  rp[base + 1] = excl + v.x;
  rp[base + 2] = excl + v.x + v.y;
  rp[base + 3] = excl + v.x + v.y + v.z;
  if (t == 255) bsum[b] = woff + incl;
}

__global__ void scan2_kernel(const int* __restrict__ bsum, int* __restrict__ boff,
                             int* __restrict__ rp) {
  __shared__ int w0;
  int t = threadIdx.x;  // 128 threads
  int v = (t < 100) ? bsum[t] : 0;
  int lane = t & 63;
  int incl = v;
  for (int off = 1; off < 64; off <<= 1) {
    int u = __shfl_up(incl, off);
    if (lane >= off) incl += u;
  }
  if (t == 63) w0 = incl;
  __syncthreads();
  int excl = incl - v + ((t >= 64) ? w0 : 0);
  if (t < 100) boff[t] = excl;
  if (t == 99) rp[SCAN_N] = excl + v;
}

__global__ __launch_bounds__(256) void scan3_kernel(int* __restrict__ rp,
                                                    const int* __restrict__ boff) {
  int b = blockIdx.x;
  int off = boff[b];
  int i = b * 1024 + threadIdx.x * 4;
  int4 v = *(int4*)(rp + i);
  v.x += off; v.y += off; v.z += off; v.w += off;
  *(int4*)(rp + i) = v;
}

__global__ void fill_kernel(const int* __restrict__ ei, const int* __restrict__ rp,
                            int* pos, int* __restrict__ col) {
  int e = blockIdx.x * blockDim.x + threadIdx.x;
  if (e >= EE) return;
  int s = ei[e], d = ei[EE + e];
  int p = atomicAdd(&pos[d], 1);
  col[rp[d] + p] = s;
  int q = atomicAdd(&pos[NN + s], 1);
  col[rp[NN + s] + q] = d;
}

// ---------------- layer-1: fin=3 linear + al_s/al_d fused (H=4,C=64) ----------------
__global__ __launch_bounds__(256) void lin1_al_kernel(const float* __restrict__ x,
                                                      const float* __restrict__ W,
                                                      const float* __restrict__ a_src,
                                                      const float* __restrict__ a_dst,
                                                      float* __restrict__ out,
                                                      float* __restrict__ al_s,
                                                      float* __restrict__ al_d,
                                                      int c1, int c2) {
  int n = blockIdx.x;
  int j = threadIdx.x;
  int wv = j >> 6, lane = j & 63;
  float f0 = x[n * 5], f1 = x[n * 5 + c1], f2 = x[n * 5 + c2];
  float v = f0 * W[j] + f1 * W[256 + j] + f2 * W[512 + j];
  out[(size_t)n * 256 + j] = v;
  float ps = v * a_src[j], pd = v * a_dst[j];  // head == wave (C=64)
  for (int off = 1; off < 64; off <<= 1) {
    ps += __shfl_xor(ps, off);
    pd += __shfl_xor(pd, off);
  }
  if (lane == 0) {
    al_s[n * 4 + wv] = ps;
    al_d[n * 4 + wv] = pd;
  }
}

// ---------------- normalized attention weights per edge (8 lanes per node) ----------
// XCD-swizzled: 1600 blocks, graph g handled by blocks with b%8 == g%8.
template <int HH>
__global__ __launch_bounds__(256) void alpha_kernel(const float* __restrict__ als,
                                                    const float* __restrict__ ald,
                                                    const int* __restrict__ rp,
                                                    const int* __restrict__ col,
                                                    float* __restrict__ alpha,
                                                    float* __restrict__ alpha_self) {
  int b = blockIdx.x;
  int xcd = b & 7, q = b >> 3;
  int g = (q / 25) * 8 + xcd;
  int d = g * 800 + (q % 25) * 32 + (threadIdx.x >> 3);
  int slot = threadIdx.x & 7;
  float ald_loc[HH], self_lg[HH];
#pragma unroll
  for (int h = 0; h < HH; h++) {
    ald_loc[h] = ald[d * HH + h];
    self_lg[h] = leaky(als[d * HH + h] + ald_loc[h]);
  }
  int beg = rp[d], end = rp[d + 1];
  int i0 = beg + slot;
  bool have = i0 < end;
  int s0 = col[have ? i0 : beg];
  float mx[HH], lg0[HH];
#pragma unroll
  for (int h = 0; h < HH; h++) mx[h] = self_lg[h];
  if (have) {
#pragma unroll
    for (int h = 0; h < HH; h++) {
      lg0[h] = leaky(als[s0 * HH + h] + ald_loc[h]);
      mx[h] = fmaxf(mx[h], lg0[h]);
    }
  }
  for (int i = i0 + 8; i < end; i += 8) {  // deg > 8 tail
    int s = col[i];
#pragma unroll
    for (int h = 0; h < HH; h++) mx[h] = fmaxf(mx[h], leaky(als[s * HH + h] + ald_loc[h]));
  }
#pragma unroll
  for (int h = 0; h < HH; h++) {
    mx[h] = fmaxf(mx[h], __shfl_xor(mx[h], 1));
    mx[h] = fmaxf(mx[h], __shfl_xor(mx[h], 2));
    mx[h] = fmaxf(mx[h], __shfl_xor(mx[h], 4));
  }
  float sm[HH], w0[HH];
#pragma unroll
  for (int h = 0; h < HH; h++) sm[h] = 0.f;
  if (have) {
#pragma unroll
    for (int h = 0; h < HH; h++) {
      w0[h] = __expf(lg0[h] - mx[h]);
      sm[h] += w0[h];
    }
  }
  for (int i = i0 + 8; i < end; i += 8) {
    int s = col[i];
#pragma unroll
    for (int h = 0; h < HH; h++) {
      float w = __expf(leaky(als[s * HH + h] + ald_loc[h]) - mx[h]);
      sm[h] += w;
      alpha[(size_t)i * HH + h] = w;
    }
  }
#pragma unroll
  for (int h = 0; h < HH; h++) {
    sm[h] += __shfl_xor(sm[h], 1);
    sm[h] += __shfl_xor(sm[h], 2);
    sm[h] += __shfl_xor(sm[h], 4);
  }
  float inv[HH];
#pragma unroll
  for (int h = 0; h < HH; h++)
    inv[h] = 1.f / (sm[h] + __expf(self_lg[h] - mx[h]) + 1e-16f);
  if (have) {
#pragma unroll
    for (int h = 0; h < HH; h++) alpha[(size_t)i0 * HH + h] = w0[h] * inv[h];
  }
  for (int i = i0 + 8; i < end; i += 8)
#pragma unroll
    for (int h = 0; h < HH; h++) alpha[(size_t)i * HH + h] *= inv[h];
  if (slot == 0) {
#pragma unroll
    for (int h = 0; h < HH; h++)
      alpha_self[d * HH + h] = __expf(self_lg[h] - mx[h]) * inv[h];
  }
}

// ---------------- SpMM: out[d]=sum alpha[e]*xp[col[e]] (2x32 lanes, 4 edges/iter) ----
// XCD-swizzled: graph's 800KB xp working set stays in one XCD's L2.
template <int HH, int CC>
__global__ __launch_bounds__(256) void spmm_kernel(const float* __restrict__ xp,
                                                   const float* __restrict__ alpha,
                                                   const float* __restrict__ alpha_self,
                                                   const int* __restrict__ rp,
                                                   const int* __restrict__ col,
                                                   const float* __restrict__ bias,
                                                   float* __restrict__ out,
                                                   __hip_bfloat16* __restrict__ out_bf,
                                                   int out_off, int do_elu) {
  constexpr int HC = HH * CC;
  constexpr int CPL = HC / 32;   // channels per lane (32 lanes per edge)
  constexpr int NV = CPL / 4;    // float4 loads per row chunk
  int b = blockIdx.x;
  int xcd = b & 7, q = b >> 3;
  int g_id = (q / 200) * 8 + xcd;
  int d = g_id * 800 + (q % 200) * 4 + (threadIdx.x >> 6);
  int lane = threadIdx.x & 63;
  int sub = lane & 31, g = lane >> 5;
  int h_l = (sub * CPL) / CC;
  size_t rowoff = (size_t)sub * CPL;
  float acc[CPL];
#pragma unroll
  for (int j = 0; j < CPL; j++) acc[j] = 0.f;
  int beg = rp[d], end = rp[d + 1];
  int deg = end - beg;
  if (g == 0) {  // self loop
    float a = alpha_self[d * HH + h_l];
    const float4* rb = (const float4*)(xp + (size_t)d * HC + rowoff);
#pragma unroll
    for (int q2 = 0; q2 < NV; q2++) {
      float4 w = rb[q2];
      acc[4 * q2 + 0] += a * w.x;
      acc[4 * q2 + 1] += a * w.y;
      acc[4 * q2 + 2] += a * w.z;
      acc[4 * q2 + 3] += a * w.w;
    }
  }
  // 4 edges in flight per iteration: each lane group chains 2 independent edges
  for (int it = 0; it * 4 < deg; it++) {
    int e1 = beg + it * 4 + g;
    int e2 = e1 + 2;
    bool p1 = e1 < end, p2 = e2 < end;
    int ec1 = p1 ? e1 : beg, ec2 = p2 ? e2 : beg;
    int s1 = col[ec1], s2 = col[ec2];
    float a1 = p1 ? alpha[(size_t)ec1 * HH + h_l] : 0.f;
    float a2 = p2 ? alpha[(size_t)ec2 * HH + h_l] : 0.f;
    const float4* rb1 = (const float4*)(xp + (size_t)s1 * HC + rowoff);
    const float4* rb2 = (const float4*)(xp + (size_t)s2 * HC + rowoff);
#pragma unroll
    for (int q2 = 0; q2 < NV; q2++) {
      float4 w1 = rb1[q2];
      float4 w2 = rb2[q2];
      acc[4 * q2 + 0] += a1 * w1.x + a2 * w2.x;
      acc[4 * q2 + 1] += a1 * w1.y + a2 * w2.y;
      acc[4 * q2 + 2] += a1 * w1.z + a2 * w2.z;
      acc[4 * q2 + 3] += a1 * w1.w + a2 * w2.w;
    }
  }
#pragma unroll
  for (int j = 0; j < CPL; j++) acc[j] += __shfl_xor(acc[j], 32);
  if (g == 0) {
    float v[CPL];
#pragma unroll
    for (int j = 0; j < CPL; j++) {
      v[j] = acc[j] + bias[sub * CPL + j];
      if (do_elu) v[j] = v[j] > 0.f ? v[j] : (__expf(v[j]) - 1.f);
    }
    if (out) {
#pragma unroll
      for (int j = 0; j < CPL; j += 4)
        *(float4*)(out + (size_t)d * 256 + out_off + sub * CPL + j) =
            make_float4(v[j], v[j + 1], v[j + 2], v[j + 3]);
    }
    if (out_bf) {
      unsigned* ob = (unsigned*)out_bf + (size_t)d * (HC / 2) + sub * (CPL / 2);
#pragma unroll
      for (int q2 = 0; q2 < CPL / 2; q2++)
        ob[q2] = (unsigned)f2b(v[2 * q2]) | ((unsigned)f2b(v[2 * q2 + 1]) << 16);
    }
  }
}

// ---------------- weight cast + transpose + K-pad: Wt[n][k] ----------------
__global__ void castW_kernel(const float* __restrict__ W, __hip_bfloat16* __restrict__ Wt,
                             int K, int N, int Kp) {
  int idx = blockIdx.x * 256 + threadIdx.x;
  if (idx >= N * Kp) return;
  int n = idx / Kp, k = idx % Kp;
  Wt[idx] = (k < K) ? __float2bfloat16(W[(size_t)k * N + n]) : __float2bfloat16(0.f);
}

// ---------------- bf16 MFMA GEMM: C[M,N] = A[M,K] @ Bt[N,K]^T ----------------
// EPI: 1 = fp32 out, 2 = bf16 tanh(x+bias) out.
// ALH > 0: also emit al_s/al_d = rowwise dot with a_src/a_dst (per-head, ALCC ch/head).
template <int EPI, int ALH, int ALCC>
__global__ __launch_bounds__(256) void gemm_mfma(const __hip_bfloat16* __restrict__ A,
                                                 const __hip_bfloat16* __restrict__ Bt,
                                                 float* __restrict__ Cf,
                                                 __hip_bfloat16* __restrict__ Cb,
                                                 const float* __restrict__ bias,
                                                 const float* __restrict__ asv,
                                                 const float* __restrict__ adv,
                                                 float* __restrict__ al_s,
                                                 float* __restrict__ al_d,
                                                 int M, int N, int K) {
  __shared__ __align__(16) __hip_bfloat16 As[128 * 32];
  __shared__ __align__(16) __hip_bfloat16 Bs[128 * 32];
  int t = threadIdx.x;
  int wave = t >> 6, lane = t & 63;
  int wm = (wave >> 1) * 64, wn = (wave & 1) * 64;
  int bm = blockIdx.y * 128, bn = blockIdx.x * 128;

  int r0 = t >> 2, c0 = (t & 3) * 8;
  const __hip_bfloat16* Ag0 = A + (size_t)(bm + r0) * K + c0;
  const __hip_bfloat16* Ag1 = A + (size_t)(bm + r0 + 64) * K + c0;
  const __hip_bfloat16* Bg0 = Bt + (size_t)(bn + r0) * K + c0;
  const __hip_bfloat16* Bg1 = Bt + (size_t)(bn + r0 + 64) * K + c0;
  __hip_bfloat16* Asp0 = As + r0 * 32 + c0;
  __hip_bfloat16* Asp1 = As + (r0 + 64) * 32 + c0;
  __hip_bfloat16* Bsp0 = Bs + r0 * 32 + c0;
  __hip_bfloat16* Bsp1 = Bs + (r0 + 64) * 32 + c0;

  f32x4 acc[4][4];
#pragma unroll
  for (int i = 0; i < 4; i++)
#pragma unroll
    for (int j = 0; j < 4; j++) acc[i][j] = (f32x4)(0.f);

  int frag_off = (lane & 15) * 32 + (lane >> 4) * 8;
  const __hip_bfloat16* Ab = As + wm * 32 + frag_off;
  const __hip_bfloat16* Bb = Bs + wn * 32 + frag_off;

  for (int k0 = 0; k0 < K; k0 += 32) {
    int4 a0 = *(const int4*)(Ag0 + k0);
    int4 a1 = *(const int4*)(Ag1 + k0);
    int4 b0 = *(const int4*)(Bg0 + k0);
    int4 b1 = *(const int4*)(Bg1 + k0);
    __syncthreads();
    *(int4*)Asp0 = a0;
    *(int4*)Asp1 = a1;
    *(int4*)Bsp0 = b0;
    *(int4*)Bsp1 = b1;
    __syncthreads();
    bf16x8 af[4], bfr[4];
#pragma unroll
    for (int i = 0; i < 4; i++) af[i] = *(const bf16x8*)(Ab + i * 16 * 32);
#pragma unroll
    for (int j = 0; j < 4; j++) bfr[j] = *(const bf16x8*)(Bb + j * 16 * 32);
#pragma unroll
    for (int i = 0; i < 4; i++)
#pragma unroll
      for (int j = 0; j < 4; j++)
        acc[i][j] = __builtin_amdgcn_mfma_f32_16x16x32_bf16(af[i], bfr[j], acc[i][j], 0, 0, 0);
  }

  int cr = (lane >> 4) * 4, cc = lane & 15;

  if constexpr (ALH > 0) {
    int head = (bn + wn) / ALCC;
    float as_c[4], ad_c[4];
#pragma unroll
    for (int j = 0; j < 4; j++) {
      int colx = bn + wn + j * 16 + cc;
      as_c[j] = asv[colx];
      ad_c[j] = adv[colx];
    }
#pragma unroll
    for (int i = 0; i < 4; i++)
#pragma unroll
      for (int r = 0; r < 4; r++) {
        float ps = 0.f, pd = 0.f;
#pragma unroll
        for (int j = 0; j < 4; j++) {
          ps += acc[i][j][r] * as_c[j];
          pd += acc[i][j][r] * ad_c[j];
        }
        ps += __shfl_xor(ps, 1); pd += __shfl_xor(pd, 1);
        ps += __shfl_xor(ps, 2); pd += __shfl_xor(pd, 2);
        ps += __shfl_xor(ps, 4); pd += __shfl_xor(pd, 4);
        ps += __shfl_xor(ps, 8); pd += __shfl_xor(pd, 8);
        if ((lane & 15) == 0) {
          int row = bm + wm + i * 16 + cr + r;
          if (ALCC > 64) {
            atomicAdd(&al_s[row * ALH + head], ps);
            atomicAdd(&al_d[row * ALH + head], pd);
          } else {
            al_s[row * ALH + head] = ps;
            al_d[row * ALH + head] = pd;
          }
        }
      }
  }

#pragma unroll
  for (int i = 0; i < 4; i++)
#pragma unroll
    for (int j = 0; j < 4; j++) {
      int colx = bn + wn + j * 16 + cc;
      float bs = (EPI == 2) ? bias[colx] : 0.f;
#pragma unroll
      for (int r = 0; r < 4; r++) {
        float v = acc[i][j][r];
        size_t off = (size_t)(bm + wm + i * 16 + cr + r) * N + colx;
        if (EPI == 2) {
          Cb[off] = __float2bfloat16(tanhf(v + bs));
        } else {
          Cf[off] = v;
        }
      }
    }
}

// ---------------- graph mean pooling (two stage) ----------------
__global__ void pool1_kernel(const float* __restrict__ h_node, float* __restrict__ part) {
  int g = blockIdx.y, c = blockIdx.x, t = threadIdx.x;
  const float* base = h_node + ((size_t)g * NPG + c * 100) * 256 + t;
  float s = 0.f;
  for (int i = 0; i < 100; i++) s += base[(size_t)i * 256];
  part[(size_t)(g * 8 + c) * 256 + t] = s;
}

__global__ void pool2_kernel(const float* __restrict__ part, float* __restrict__ g_pool) {
  int g = blockIdx.x, t = threadIdx.x;
  float s = 0.f;
  for (int c = 0; c < 8; c++) s += part[(size_t)(g * 8 + c) * 256 + t];
  g_pool[g * 256 + t] = s * (1.f / NPG);
}

// ---------------- build MLP input features (bf16, padded to KF) ----------------
__global__ __launch_bounds__(256) void buildfeat_kernel(const float* __restrict__ h_node,
                                                        const float* __restrict__ g_pool,
                                                        const int* __restrict__ actions,
                                                        const float* __restrict__ tabu,
                                                        const int* __restrict__ batch,
                                                        __hip_bfloat16* __restrict__ feat) {
  int a = (blockIdx.x * blockDim.x + threadIdx.x) >> 6;
  int lane = threadIdx.x & 63;
  if (a >= NA) return;
  int n0 = actions[a * 2], n1 = actions[a * 2 + 1];
  int g = batch[n0];
  float4 v0 = *(const float4*)(h_node + (size_t)n0 * 256 + lane * 4);
  float4 vg = *(const float4*)(g_pool + (size_t)g * 256 + lane * 4);
  float4 v1 = *(const float4*)(h_node + (size_t)n1 * 256 + lane * 4);
  __hip_bfloat16* fr = feat + (size_t)a * KF;
  ushort4 u;
  u = make_ushort4(f2b(v0.x), f2b(v0.y), f2b(v0.z), f2b(v0.w));
  *(ushort4*)(fr + lane * 4) = u;
  u = make_ushort4(f2b(vg.x), f2b(vg.y), f2b(vg.z), f2b(vg.w));
  *(ushort4*)(fr + 256 + lane * 4) = u;
  u = make_ushort4(f2b(v1.x), f2b(v1.y), f2b(v1.z), f2b(v1.w));
  *(ushort4*)(fr + 512 + lane * 4) = u;
  u = make_ushort4(f2b(vg.x), f2b(vg.y), f2b(vg.z), f2b(vg.w));
  *(ushort4*)(fr + 768 + lane * 4) = u;
  if (lane < 8) {
    float t0 = (lane == 0) ? tabu[a] : 0.f;
    u = make_ushort4(f2b(t0), 0, 0, 0);
    *(ushort4*)(fr + 1024 + lane * 4) = u;
  }
}

// ---------------- final layer GEMV: scores = y @ W4 + b4 ----------------
__global__ __launch_bounds__(256) void gemv_kernel(const __hip_bfloat16* __restrict__ y,
                                                   const float* __restrict__ W4,
                                                   const float* __restrict__ b4,
                                                   float* __restrict__ scores) {
  int a = (blockIdx.x * blockDim.x + threadIdx.x) >> 6;
  int lane = threadIdx.x & 63;
  if (a >= NA) return;
  const unsigned* row = (const unsigned*)(y + (size_t)a * 256);
  float s = 0.f;
#pragma unroll
  for (int q = 0; q < 2; q++) {
    unsigned w = row[lane * 2 + q];
    float lo = __uint_as_float(w << 16), hi = __uint_as_float(w & 0xffff0000u);
    s += lo * W4[lane * 4 + 2 * q] + hi * W4[lane * 4 + 2 * q + 1];
  }
  for (int off = 1; off < 64; off <<= 1) s += __shfl_xor(s, off);
  if (lane == 0) scores[a] = s + b4[0];
}

// ---------------- log-softmax + entropy per graph ----------------
__global__ void softmax_kernel(const float* __restrict__ scores, float* __restrict__ out) {
  int g = (blockIdx.x * blockDim.x + threadIdx.x) >> 6;
  int lane = threadIdx.x & 63;
  if (g >= BB) return;
  float s = scores[g * 64 + lane];
  float m = s;
  for (int off = 1; off < 64; off <<= 1) m = fmaxf(m, __shfl_xor(m, off));
  float ex = expf(s - m);
  float sum = ex;
  for (int off = 1; off < 64; off <<= 1) sum += __shfl_xor(sum, off);
  float lp = s - m - logf(sum);
  out[g * 64 + lane] = lp;
  float pe = (ex / sum) * lp;
  for (int off = 1; off < 64; off <<= 1) pe += __shfl_xor(pe, off);
  if (lane == 0) out[BB * APG + g] = -pe;
}

extern "C" void kernel_launch(void* const* d_in, const int* in_sizes, int n_in,
                              void* d_out, int out_size, void* d_ws, size_t ws_size,
                              hipStream_t stream) {
  const float* x = (const float*)d_in[0];
  const int* ei = (const int*)d_in[1];
  const int* batch = (const int*)d_in[2];
  const int* actions = (const int*)d_in[3];
  const float* tabu = (const float*)d_in[4];
  const float* pW1 = (const float*)d_in[29];
  const float* pb1 = (const float*)d_in[30];
  const float* pW2 = (const float*)d_in[31];
  const float* pb2 = (const float*)d_in[32];
  const float* pW3 = (const float*)d_in[33];
  const float* pb3 = (const float*)d_in[34];
  const float* pW4 = (const float*)d_in[35];
  const float* pb4 = (const float*)d_in[36];
  float* out = (float*)d_out;

  char* ws = (char*)d_ws;
  size_t o = 0;
  auto alloc = [&](size_t bytes) -> void* {
    o = (o + 255) & ~(size_t)255;
    void* p = ws + o;
    o += bytes;
    return p;
  };
  int* cnt = (int*)alloc((size_t)4 * NN * 4);  // cnt[2NN] + pos[2NN]
  int* rp = (int*)alloc((size_t)(SCAN_N + 1) * 4);
  int* col = (int*)alloc(((size_t)2 * EE + 64) * 4);
  int* bsum = (int*)alloc(128 * 4);
  int* boff = (int*)alloc(128 * 4);
  float* al_s = (float*)alloc((size_t)NN * 4 * 4);
  float* al_d = (float*)alloc((size_t)NN * 4 * 4);
  float* alpha = (float*)alloc((size_t)2 * EE * 4 * 4);
  float* alpha_self = (float*)alloc((size_t)NN * 4 * 4);
  float* bufXf = (float*)alloc((size_t)NN * 256 * 4);                   // xp fp32
  __hip_bfloat16* bufA = (__hip_bfloat16*)alloc((size_t)NN * 256 * 2);  // agg out -> GEMM A
  float* h_node = (float*)alloc((size_t)NN * 256 * 4);
  __hip_bfloat16* wt = (__hip_bfloat16*)alloc((size_t)256 * KF * 2);
  float* part = (float*)alloc((size_t)BB * 8 * 256 * 4);
  float* g_pool = (float*)alloc((size_t)BB * 256 * 4);
  float* scores = (float*)alloc((size_t)NA * 4);
  // MLP scratch aliased onto bufXf (dead after last spmm)
  __hip_bfloat16* feat = (__hip_bfloat16*)bufXf;
  __hip_bfloat16* y1 = feat + (size_t)NA * KF;
  __hip_bfloat16* y2 = y1 + (size_t)NA * 256;

  // --- CSR build ---
  hipMemsetAsync(cnt, 0, (size_t)4 * NN * 4, stream);
  count_kernel<<<(EE + 255) / 256, 256, 0, stream>>>(ei, cnt);
  scan1_kernel<<<SCAN_N / 1024, 256, 0, stream>>>(cnt, rp, bsum);
  scan2_kernel<<<1, 128, 0, stream>>>(bsum, boff, rp);
  scan3_kernel<<<SCAN_N / 1024, 256, 0, stream>>>(rp, boff);
  fill_kernel<<<(EE + 255) / 256, 256, 0, stream>>>(ei, rp, cnt + 2 * NN, col);

  const int nwb = NN / 4;        // spmm: wave per node (XCD-swizzled)
  const int nab = NN * 8 / 256;  // alpha: 8 lanes per node (XCD-swizzled)
  for (int dir = 0; dir < 2; dir++) {
    const int* rpd = dir ? (rp + NN) : rp;
    int base = 5 + dir * 12;
    const float* W0 = (const float*)d_in[base + 0];
    const float* as0 = (const float*)d_in[base + 1];
    const float* ad0 = (const float*)d_in[base + 2];
    const float* b0 = (const float*)d_in[base + 3];
    const float* W1 = (const float*)d_in[base + 4];
    const float* as1 = (const float*)d_in[base + 5];
    const float* ad1 = (const float*)d_in[base + 6];
    const float* b1 = (const float*)d_in[base + 7];
    const float* W2 = (const float*)d_in[base + 8];
    const float* as2 = (const float*)d_in[base + 9];
    const float* ad2 = (const float*)d_in[base + 10];
    const float* b2 = (const float*)d_in[base + 11];
    int c1 = dir ? 2 : 1, c2 = dir ? 4 : 3;

    // layer 1 (fin=3, H=4, C=64)
    lin1_al_kernel<<<NN, 256, 0, stream>>>(x, W0, as0, ad0, bufXf, al_s, al_d, c1, c2);
    alpha_kernel<4><<<nab, 256, 0, stream>>>(al_s, al_d, rpd, col, alpha, alpha_self);
    spmm_kernel<4, 64><<<nwb, 256, 0, stream>>>(bufXf, alpha, alpha_self, rpd, col, b0,
                                                nullptr, bufA, 0, 1);
    // layer 2 (256 -> H4C64), al fused into GEMM epilogue
    castW_kernel<<<(256 * 256 + 255) / 256, 256, 0, stream>>>(W1, wt, 256, 256, 256);
    gemm_mfma<1, 4, 64><<<dim3(2, NN / 128), 256, 0, stream>>>(
        bufA, wt, bufXf, nullptr, nullptr, as1, ad1, al_s, al_d, NN, 256, 256);
    alpha_kernel<4><<<nab, 256, 0, stream>>>(al_s, al_d, rpd, col, alpha, alpha_self);
    spmm_kernel<4, 64><<<nwb, 256, 0, stream>>>(bufXf, alpha, alpha_self, rpd, col, b1,
                                                nullptr, bufA, 0, 1);
    // layer 3 (256 -> H1C128, no elu) -> h_node half (fp32); al fused (atomic halves)
    castW_kernel<<<(128 * 256 + 255) / 256, 256, 0, stream>>>(W2, wt, 256, 128, 256);
    hipMemsetAsync(al_s, 0, (size_t)NN * 4, stream);
    hipMemsetAsync(al_d, 0, (size_t)NN * 4, stream);
    gemm_mfma<1, 1, 128><<<dim3(1, NN / 128), 256, 0, stream>>>(
        bufA, wt, bufXf, nullptr, nullptr, as2, ad2, al_s, al_d, NN, 128, 256);
    alpha_kernel<1><<<nab, 256, 0, stream>>>(al_s, al_d, rpd, col, alpha, alpha_self);
    spmm_kernel<1, 128><<<nwb, 256, 0, stream>>>(bufXf, alpha, alpha_self, rpd, col, b2,
                                                 h_node, nullptr, dir * 128, 0);
  }

  pool1_kernel<<<dim3(8, BB), 256, 0, stream>>>(h_node, part);
  pool2_kernel<<<BB, 256, 0, stream>>>(part, g_pool);

  // --- MLP head via MFMA ---
  buildfeat_kernel<<<NA / 4, 256, 0, stream>>>(h_node, g_pool, actions, tabu, batch, feat);
  castW_kernel<<<(256 * KF + 255) / 256, 256, 0, stream>>>(pW1, wt, 1025, 256, KF);
  gemm_mfma<2, 0, 64><<<dim3(2, NA / 128), 256, 0, stream>>>(
      feat, wt, nullptr, y1, pb1, nullptr, nullptr, nullptr, nullptr, NA, 256, KF);
  castW_kernel<<<(256 * 256 + 255) / 256, 256, 0, stream>>>(pW2, wt, 256, 256, 256);
  gemm_mfma<2, 0, 64><<<dim3(2, NA / 128), 256, 0, stream>>>(
      y1, wt, nullptr, y2, pb2, nullptr, nullptr, nullptr, nullptr, NA, 256, 256);
  castW_kernel<<<(256 * 256 + 255) / 256, 256, 0, stream>>>(pW3, wt, 256, 256, 256);
  gemm_mfma<2, 0, 64><<<dim3(2, NA / 128), 256, 0, stream>>>(
      y2, wt, nullptr, y1, pb3, nullptr, nullptr, nullptr, nullptr, NA, 256, 256);
  gemv_kernel<<<NA / 4, 256, 0, stream>>>(y1, pW4, pb4, scores);
  softmax_kernel<<<(BB * 64) / 256, 256, 0, stream>>>(scores, out);
}